// Round 3
// baseline (1532.118 us; speedup 1.0000x reference)
//
#include <hip/hip_runtime.h>
#include <stdint.h>

#define HID 2048

// ---------------- threefry2x32 (JAX-compatible) ----------------
__device__ __forceinline__ uint32_t rotl32(uint32_t v, int r){ return (v<<r)|(v>>(32-r)); }

__device__ __forceinline__ void tf2x32(uint32_t k0, uint32_t k1, uint32_t x0, uint32_t x1,
                                       uint32_t& o0, uint32_t& o1){
  uint32_t ks2 = k0 ^ k1 ^ 0x1BD11BDAu;
  x0 += k0; x1 += k1;
  x0+=x1; x1=rotl32(x1,13); x1^=x0;
  x0+=x1; x1=rotl32(x1,15); x1^=x0;
  x0+=x1; x1=rotl32(x1,26); x1^=x0;
  x0+=x1; x1=rotl32(x1,6);  x1^=x0;
  x0+=k1; x1+=ks2+1u;
  x0+=x1; x1=rotl32(x1,17); x1^=x0;
  x0+=x1; x1=rotl32(x1,29); x1^=x0;
  x0+=x1; x1=rotl32(x1,16); x1^=x0;
  x0+=x1; x1=rotl32(x1,24); x1^=x0;
  x0+=ks2; x1+=k0+2u;
  x0+=x1; x1=rotl32(x1,13); x1^=x0;
  x0+=x1; x1=rotl32(x1,15); x1^=x0;
  x0+=x1; x1=rotl32(x1,26); x1^=x0;
  x0+=x1; x1=rotl32(x1,6);  x1^=x0;
  x0+=k0; x1+=k1+3u;
  x0+=x1; x1=rotl32(x1,17); x1^=x0;
  x0+=x1; x1=rotl32(x1,29); x1^=x0;
  x0+=x1; x1=rotl32(x1,16); x1^=x0;
  x0+=x1; x1=rotl32(x1,24); x1^=x0;
  x0+=k1; x1+=ks2+4u;
  x0+=x1; x1=rotl32(x1,13); x1^=x0;
  x0+=x1; x1=rotl32(x1,15); x1^=x0;
  x0+=x1; x1=rotl32(x1,26); x1^=x0;
  x0+=x1; x1=rotl32(x1,6);  x1^=x0;
  x0+=ks2; x1+=k0+5u;
  o0=x0; o1=x1;
}

// jax.random.categorical with jax_threefry_partitionable=True (verified R2: absmax 0)
__device__ void do_sample(const float* logits, int k, uint32_t* key, float* sc,
                          int* action_out, int* xidx, int xoff){
  float m = logits[0];
  for (int i=1;i<k;i++) m = fmaxf(m, logits[i]);
  float se = 0.f;
  for (int i=0;i<k;i++) se += expf(logits[i]-m);
  float lse = logf(se);

  uint32_t n0,n1,s0,s1;
  tf2x32(key[0],key[1],0u,0u,n0,n1);
  tf2x32(key[0],key[1],0u,1u,s0,s1);
  key[0]=n0; key[1]=n1;

  float best=-3.0e38f; int act=0;
  for (int i=0;i<k;i++){
    uint32_t y0,y1; tf2x32(s0,s1,0u,(uint32_t)i,y0,y1);
    uint32_t bits = y0 ^ y1;
    float f = __uint_as_float((bits>>9)|0x3f800000u) - 1.0f;
    float u = fmaxf(f, 1.17549435e-38f);
    float g = -logf(-logf(u));
    float z = logits[i]+g;
    if (z>best){best=z; act=i;}
  }
  float ent=0.f;
  for (int i=0;i<k;i++){ float lp=logits[i]-m-lse; ent -= lp*expf(lp); }
  sc[0] += logits[act]-m-lse;
  sc[1] += ent;
  *action_out = act;
  *xidx = act + xoff;
}

__device__ __forceinline__ float wave_reduce(float v){
  #pragma unroll
  for (int s=32;s;s>>=1) v += __shfl_xor(v, s);
  return v;
}

// ---------------- init ----------------
__global__ void init_kernel(float* h0, float* c, float* sc, uint32_t* key, int* xidx,
                            int* counters){
  int tid = blockIdx.x*blockDim.x + threadIdx.x;
  if (tid < HID){ h0[tid]=0.f; c[tid]=0.f; }
  if (tid < 32) counters[tid] = 0;
  if (tid==0){ sc[0]=0.f; sc[1]=0.f; key[0]=0u; key[1]=42u; xidx[0]=19; }
}

// ---------------- E = emb[0:8] @ W_emb_attn.T : block per output column w ----------------
__global__ __launch_bounds__(256) void eproj_kernel(const float* __restrict__ emb,
                                                    const float* __restrict__ Wq,
                                                    float* __restrict__ E){
  __shared__ float red[4][8];
  int w = blockIdx.x;
  int wid = threadIdx.x >> 6, lane = threadIdx.x & 63;
  const float4* W4 = (const float4*)(Wq + (size_t)w*HID) + wid*128;
  float acc[8];
  #pragma unroll
  for (int i=0;i<8;i++) acc[i]=0.f;
  #pragma unroll
  for (int it=0; it<2; ++it){
    float4 wv = W4[it*64 + lane];
    #pragma unroll
    for (int i=0;i<8;i++){
      float4 ev = (((const float4*)(emb + (size_t)i*HID)) + wid*128)[it*64+lane];
      acc[i] += wv.x*ev.x + wv.y*ev.y + wv.z*ev.z + wv.w*ev.w;
    }
  }
  #pragma unroll
  for (int i=0;i<8;i++){
    float v = wave_reduce(acc[i]);
    if (lane==0) red[wid][i]=v;
  }
  __syncthreads();
  if (threadIdx.x < 8){
    int i = threadIdx.x;
    E[(size_t)i*HID + w] = red[0][i]+red[1][i]+red[2][i]+red[3][i];
  }
}

// ---------------- P[e] = W_ih@emb[e] + b : block per gate-row j ----------------
__global__ __launch_bounds__(256) void pproj_kernel(const float* __restrict__ Wih,
                                                    const float* __restrict__ emb,
                                                    const float* __restrict__ bih,
                                                    const float* __restrict__ bhh,
                                                    float* __restrict__ P){
  __shared__ float red[4][19];
  int j = blockIdx.x;
  int wid = threadIdx.x >> 6, lane = threadIdx.x & 63;
  const float4* W4 = (const float4*)(Wih + (size_t)j*HID) + wid*128;
  float acc[19];
  #pragma unroll
  for (int e=0;e<19;e++) acc[e]=0.f;
  #pragma unroll
  for (int it=0; it<2; ++it){
    float4 wv = W4[it*64 + lane];
    #pragma unroll
    for (int e=0;e<19;e++){
      float4 ev = (((const float4*)(emb + (size_t)e*HID)) + wid*128)[it*64+lane];
      acc[e] += wv.x*ev.x + wv.y*ev.y + wv.z*ev.z + wv.w*ev.w;
    }
  }
  #pragma unroll
  for (int e=0;e<19;e++){
    float v = wave_reduce(acc[e]);
    if (lane==0) red[wid][e]=v;
  }
  __syncthreads();
  if (threadIdx.x < 19){
    int e = threadIdx.x;
    float b = bih[j] + bhh[j];
    P[(size_t)e*4*HID + j] = red[0][e]+red[1][e]+red[2][e]+red[3][e] + b;
    if (e==0) P[(size_t)19*4*HID + j] = b;
  }
}

// ---------------- LSTM step: block per hidden element t, wave per K-chunk ----------------
__global__ __launch_bounds__(256) void lstm_kernel(const float* __restrict__ Whh,
                                                   const float* __restrict__ P,
                                                   const int* __restrict__ xidx,
                                                   const float* __restrict__ hin,
                                                   float* __restrict__ hout,
                                                   float* __restrict__ c){
  __shared__ float red[4][4];
  int t = blockIdx.x;
  int wid = threadIdx.x >> 6, lane = threadIdx.x & 63;
  const float4* h4 = (const float4*)hin + wid*128;
  float acc[4] = {0.f,0.f,0.f,0.f};
  #pragma unroll
  for (int it=0; it<2; ++it){
    float4 hv = h4[it*64 + lane];
    #pragma unroll
    for (int g=0; g<4; ++g){
      const float4* w4 = (const float4*)(Whh + (size_t)(g*HID + t)*HID) + wid*128;
      float4 w = w4[it*64 + lane];
      acc[g] += w.x*hv.x + w.y*hv.y + w.z*hv.z + w.w*hv.w;
    }
  }
  #pragma unroll
  for (int g=0; g<4; ++g){
    float v = wave_reduce(acc[g]);
    if (lane==0) red[wid][g]=v;
  }
  __syncthreads();
  if (threadIdx.x==0){
    int xi = xidx[0];
    const float* Pr = P + (size_t)xi*4*HID;
    float gi = red[0][0]+red[1][0]+red[2][0]+red[3][0] + Pr[t];
    float gf = red[0][1]+red[1][1]+red[2][1]+red[3][1] + Pr[HID+t];
    float gg = red[0][2]+red[1][2]+red[2][2]+red[3][2] + Pr[2*HID+t];
    float go = red[0][3]+red[1][3]+red[2][3]+red[3][3] + Pr[3*HID+t];
    float si = 1.f/(1.f+expf(-gi));
    float sf = 1.f/(1.f+expf(-gf));
    float so = 1.f/(1.f+expf(-go));
    float c2 = sf*c[t] + si*tanhf(gg);
    float h2 = so*tanhf(c2);
    c[t]=c2; hout[t]=h2;
  }
}

// ---------------- fused hproj + attention logits + sample (last-block pattern) ----------------
__global__ __launch_bounds__(256) void attn_fused_kernel(const float* __restrict__ Wh,
                                                         const float* __restrict__ h,
                                                         const float* __restrict__ E,
                                                         const float* __restrict__ Wv,
                                                         float* __restrict__ partial,
                                                         int* counter,
                                                         float* sc, uint32_t* key, int* xidx,
                                                         int* action_slot, int k){
  __shared__ float red[4];
  __shared__ float sfin[8];
  __shared__ int islast;
  int j = blockIdx.x;
  int wid = threadIdx.x >> 6, lane = threadIdx.x & 63;
  const float4* W4 = (const float4*)(Wh + (size_t)j*HID) + wid*128;
  const float4* h4 = (const float4*)h + wid*128;
  float acc = 0.f;
  #pragma unroll
  for (int it=0; it<2; ++it){
    float4 w = W4[it*64+lane];
    float4 hv = h4[it*64+lane];
    acc += w.x*hv.x + w.y*hv.y + w.z*hv.z + w.w*hv.w;
  }
  acc = wave_reduce(acc);
  if (lane==0) red[wid]=acc;
  __syncthreads();
  if (threadIdx.x==0){
    float a = red[0]+red[1]+red[2]+red[3];
    float wv = Wv[j];
    for (int i=0;i<k;i++)
      partial[(size_t)i*HID + j] = tanhf(E[(size_t)i*HID + j] + a) * wv;
    __threadfence();
    int prev = atomicAdd(counter, 1);
    islast = (prev == (int)gridDim.x - 1);
  }
  __syncthreads();
  if (!islast) return;
  __threadfence();
  // deterministic fixed-order final reduction: wave wid handles i = wid, wid+4
  #pragma unroll
  for (int rep=0; rep<2; ++rep){
    int i = wid + rep*4;
    if (i < k){
      float s = 0.f;
      for (int j2 = lane; j2 < HID; j2 += 64) s += partial[(size_t)i*HID + j2];
      s = wave_reduce(s);
      if (lane==0) sfin[i] = s;
    }
  }
  __syncthreads();
  if (threadIdx.x==0){
    float logits[8];
    for (int i=0;i<k;i++) logits[i] = 2.5f * tanhf(sfin[i] * 0.2f);
    do_sample(logits, k, key, sc, action_slot, xidx, 0);
  }
}

// ---------------- fused op logits + sample (last-block pattern) ----------------
__global__ __launch_bounds__(256) void op_fused_kernel(const float* __restrict__ Wsoft,
                                                       const float* __restrict__ bsoft,
                                                       const float* __restrict__ h,
                                                       float* __restrict__ raw,
                                                       int* counter,
                                                       float* sc, uint32_t* key, int* xidx,
                                                       int* action_slot){
  __shared__ float red[4];
  __shared__ int islast;
  int i = blockIdx.x;   // 0..10
  int wid = threadIdx.x >> 6, lane = threadIdx.x & 63;
  const float4* W4 = (const float4*)(Wsoft + (size_t)i*HID) + wid*128;
  const float4* h4 = (const float4*)h + wid*128;
  float acc = 0.f;
  #pragma unroll
  for (int it=0; it<2; ++it){
    float4 w = W4[it*64+lane];
    float4 hv = h4[it*64+lane];
    acc += w.x*hv.x + w.y*hv.y + w.z*hv.z + w.w*hv.w;
  }
  acc = wave_reduce(acc);
  if (lane==0) red[wid]=acc;
  __syncthreads();
  if (threadIdx.x==0){
    raw[i] = red[0]+red[1]+red[2]+red[3] + bsoft[i];
    __threadfence();
    int prev = atomicAdd(counter, 1);
    islast = (prev == (int)gridDim.x - 1);
  }
  __syncthreads();
  if (!islast) return;
  if (threadIdx.x==0){
    __threadfence();
    float logits[11];
    for (int q=0;q<11;q++) logits[q] = tanhf(raw[q] * 0.2f);
    do_sample(logits, 11, key, sc, action_slot, xidx, 8);
  }
}

// ---------------- write outputs ----------------
__global__ void finalize_kernel(const int* __restrict__ actions, const float* __restrict__ sc,
                                float* __restrict__ out){
  int tid = threadIdx.x;
  if (tid < 28) out[tid] = (float)actions[tid];
  if (tid == 28) out[28] = sc[0];
  if (tid == 29) out[29] = sc[1];
}

extern "C" void kernel_launch(void* const* d_in, const int* in_sizes, int n_in,
                              void* d_out, int out_size, void* d_ws, size_t ws_size,
                              hipStream_t stream) {
  const float* emb   = (const float*)d_in[0];
  const float* Wq    = (const float*)d_in[1];
  const float* Wh    = (const float*)d_in[2];
  const float* Wv    = (const float*)d_in[3];
  const float* Wsoft = (const float*)d_in[4];
  const float* bsoft = (const float*)d_in[5];
  const float* Wih   = (const float*)d_in[6];
  const float* Whh   = (const float*)d_in[7];
  const float* bih   = (const float*)d_in[8];
  const float* bhh   = (const float*)d_in[9];
  float* out = (float*)d_out;

  float* ws = (float*)d_ws;
  float* h0      = ws;                    // 2048
  float* h1      = h0 + HID;              // 2048
  float* c       = h1 + HID;              // 2048
  float* E       = c  + HID;              // 8*2048
  float* P       = E  + 8*HID;            // 20*8192
  float* partial = P  + 20*4*HID;         // 8*2048
  float* raw     = partial + 8*HID;       // 16
  float* sc      = raw + 16;              // 2
  uint32_t* key  = (uint32_t*)(sc + 2);   // 2
  int* xidx      = (int*)(sc + 4);        // 1
  int* actions   = (int*)(sc + 5);        // 28
  int* counters  = (int*)(sc + 33);       // 32

  init_kernel<<<8,256,0,stream>>>(h0, c, sc, key, xidx, counters);
  eproj_kernel<<<HID,256,0,stream>>>(emb, Wq, E);
  pproj_kernel<<<4*HID,256,0,stream>>>(Wih, emb, bih, bhh, P);

  float* hbuf[2] = {h0, h1};
  int cur = 0, ns = 0, os = 0, step = 0;
  for (int node = 0; node < 7; ++node){
    for (int i = 0; i < 2; ++i){
      lstm_kernel<<<HID,256,0,stream>>>(Whh, P, xidx, hbuf[cur], hbuf[cur^1], c);
      cur ^= 1;
      attn_fused_kernel<<<HID,256,0,stream>>>(Wh, hbuf[cur], E, Wv, partial,
                                              counters + step, sc, key, xidx,
                                              actions + ns, node + 2);
      step++; ns++;
    }
    for (int i = 0; i < 2; ++i){
      lstm_kernel<<<HID,256,0,stream>>>(Whh, P, xidx, hbuf[cur], hbuf[cur^1], c);
      cur ^= 1;
      op_fused_kernel<<<11,256,0,stream>>>(Wsoft, bsoft, hbuf[cur], raw,
                                           counters + step, sc, key, xidx,
                                           actions + 14 + os);
      step++; os++;
    }
  }
  finalize_kernel<<<1,64,0,stream>>>(actions, sc, out);
}

// Round 4
// 1200.861 us; speedup vs baseline: 1.2758x; 1.2758x over previous
//
#include <hip/hip_runtime.h>
#include <stdint.h>

#define HID 2048

// ---------------- threefry2x32 (JAX-compatible) ----------------
__device__ __forceinline__ uint32_t rotl32(uint32_t v, int r){ return (v<<r)|(v>>(32-r)); }

__device__ __forceinline__ void tf2x32(uint32_t k0, uint32_t k1, uint32_t x0, uint32_t x1,
                                       uint32_t& o0, uint32_t& o1){
  uint32_t ks2 = k0 ^ k1 ^ 0x1BD11BDAu;
  x0 += k0; x1 += k1;
  x0+=x1; x1=rotl32(x1,13); x1^=x0;
  x0+=x1; x1=rotl32(x1,15); x1^=x0;
  x0+=x1; x1=rotl32(x1,26); x1^=x0;
  x0+=x1; x1=rotl32(x1,6);  x1^=x0;
  x0+=k1; x1+=ks2+1u;
  x0+=x1; x1=rotl32(x1,17); x1^=x0;
  x0+=x1; x1=rotl32(x1,29); x1^=x0;
  x0+=x1; x1=rotl32(x1,16); x1^=x0;
  x0+=x1; x1=rotl32(x1,24); x1^=x0;
  x0+=ks2; x1+=k0+2u;
  x0+=x1; x1=rotl32(x1,13); x1^=x0;
  x0+=x1; x1=rotl32(x1,15); x1^=x0;
  x0+=x1; x1=rotl32(x1,26); x1^=x0;
  x0+=x1; x1=rotl32(x1,6);  x1^=x0;
  x0+=k0; x1+=k1+3u;
  x0+=x1; x1=rotl32(x1,17); x1^=x0;
  x0+=x1; x1=rotl32(x1,29); x1^=x0;
  x0+=x1; x1=rotl32(x1,16); x1^=x0;
  x0+=x1; x1=rotl32(x1,24); x1^=x0;
  x0+=k1; x1+=ks2+4u;
  x0+=x1; x1=rotl32(x1,13); x1^=x0;
  x0+=x1; x1=rotl32(x1,15); x1^=x0;
  x0+=x1; x1=rotl32(x1,26); x1^=x0;
  x0+=x1; x1=rotl32(x1,6);  x1^=x0;
  x0+=ks2; x1+=k0+5u;
  o0=x0; o1=x1;
}

// jax.random.categorical, jax_threefry_partitionable=True (verified R2: absmax 0)
__device__ void do_sample(const float* logits, int k, uint32_t* key, float* sc,
                          int* action_out, int* xidx, int xoff){
  float m = logits[0];
  for (int i=1;i<k;i++) m = fmaxf(m, logits[i]);
  float se = 0.f;
  for (int i=0;i<k;i++) se += expf(logits[i]-m);
  float lse = logf(se);

  uint32_t n0,n1,s0,s1;
  tf2x32(key[0],key[1],0u,0u,n0,n1);
  tf2x32(key[0],key[1],0u,1u,s0,s1);
  key[0]=n0; key[1]=n1;

  float best=-3.0e38f; int act=0;
  for (int i=0;i<k;i++){
    uint32_t y0,y1; tf2x32(s0,s1,0u,(uint32_t)i,y0,y1);
    uint32_t bits = y0 ^ y1;
    float f = __uint_as_float((bits>>9)|0x3f800000u) - 1.0f;
    float u = fmaxf(f, 1.17549435e-38f);
    float g = -logf(-logf(u));
    float z = logits[i]+g;
    if (z>best){best=z; act=i;}
  }
  float ent=0.f;
  for (int i=0;i<k;i++){ float lp=logits[i]-m-lse; ent -= lp*expf(lp); }
  sc[0] += logits[act]-m-lse;
  sc[1] += ent;
  *action_out = act;
  *xidx = act + xoff;
}

__device__ __forceinline__ float wave_reduce(float v){
  #pragma unroll
  for (int s=32;s;s>>=1) v += __shfl_xor(v, s);
  return v;
}
__device__ __forceinline__ float dot4(float4 a, float4 b){
  return a.x*b.x + a.y*b.y + a.z*b.z + a.w*b.w;
}

// ---------------- init ----------------
__global__ void init_kernel(float* h0, float* c, float* sc, uint32_t* key, int* xidx,
                            int* counters){
  int tid = blockIdx.x*blockDim.x + threadIdx.x;
  if (tid < HID){ h0[tid]=0.f; c[tid]=0.f; }
  if (tid < 32) counters[tid] = 0;
  if (tid==0){ sc[0]=0.f; sc[1]=0.f; key[0]=0u; key[1]=42u; xidx[0]=19; }
}

// ---------------- E = emb[0:8] @ W_emb_attn.T (R2-proven shape) ----------------
__global__ __launch_bounds__(256) void eproj_kernel(const float* __restrict__ emb,
                                                    const float* __restrict__ Wq,
                                                    float* __restrict__ E){
  int w = (blockIdx.x*256 + threadIdx.x) >> 6;
  int lane = threadIdx.x & 63;
  if (w >= HID) return;
  const float4* W4 = (const float4*)(Wq + (size_t)w*HID);
  float acc[8];
  #pragma unroll
  for (int i=0;i<8;i++) acc[i]=0.f;
  #pragma unroll
  for (int it=0; it<8; ++it){
    float4 wv = W4[it*64 + lane];
    #pragma unroll
    for (int i=0;i<8;i++){
      float4 ev = ((const float4*)(emb + (size_t)i*HID))[it*64+lane];
      acc[i] += dot4(wv, ev);
    }
  }
  #pragma unroll
  for (int i=0;i<8;i++){
    float v = wave_reduce(acc[i]);
    if (lane==0) E[(size_t)i*HID + w] = v;
  }
}

// ---------------- pproj: LDS-staged emb, 2 rows/wave ----------------
// grid 1024 blocks x 256 thr; block handles 8 gate-rows; 4 K-chunks of 512
__global__ __launch_bounds__(256) void pproj_kernel(const float* __restrict__ Wih,
                                                    const float* __restrict__ emb,
                                                    const float* __restrict__ bih,
                                                    const float* __restrict__ bhh,
                                                    float* __restrict__ P){
  __shared__ float4 smem[19*128];   // emb[19][512] chunk
  int tid = threadIdx.x, wid = tid>>6, lane = tid&63;
  int jbase = blockIdx.x*8 + wid*2;
  float acc0[19], acc1[19];
  #pragma unroll
  for (int e=0;e<19;e++){ acc0[e]=0.f; acc1[e]=0.f; }
  for (int ch=0; ch<4; ++ch){
    __syncthreads();
    for (int t = tid; t < 19*128; t += 256){
      int row = t>>7, col = t&127;
      smem[t] = ((const float4*)(emb + (size_t)row*HID + ch*512))[col];
    }
    __syncthreads();
    #pragma unroll
    for (int it=0; it<2; ++it){
      float4 w0 = ((const float4*)(Wih + (size_t)jbase*HID     + ch*512))[it*64+lane];
      float4 w1 = ((const float4*)(Wih + (size_t)(jbase+1)*HID + ch*512))[it*64+lane];
      #pragma unroll
      for (int e=0;e<19;e++){
        float4 ev = smem[e*128 + it*64 + lane];
        acc0[e] += dot4(w0, ev);
        acc1[e] += dot4(w1, ev);
      }
    }
  }
  #pragma unroll
  for (int e=0;e<19;e++){ acc0[e]=wave_reduce(acc0[e]); acc1[e]=wave_reduce(acc1[e]); }
  if (lane==0){
    float b0 = bih[jbase]   + bhh[jbase];
    float b1 = bih[jbase+1] + bhh[jbase+1];
    #pragma unroll
    for (int e=0;e<19;e++){
      P[(size_t)e*4*HID + jbase]   = acc0[e] + b0;
      P[(size_t)e*4*HID + jbase+1] = acc1[e] + b1;
    }
    P[(size_t)19*4*HID + jbase]   = b0;
    P[(size_t)19*4*HID + jbase+1] = b1;
  }
}

// ---------------- LSTM: 512 blocks x 512 thr; block = 4 t's; wave = (t, K-half) ----------------
__global__ __launch_bounds__(512,4) void lstm_kernel(const float* __restrict__ Whh,
                                                     const float* __restrict__ P,
                                                     const int* __restrict__ xidx,
                                                     const float* __restrict__ hin,
                                                     float* __restrict__ hout,
                                                     float* __restrict__ c){
  __shared__ float4 hs4[512];       // full h (2048 f)
  __shared__ float red[8][4];
  int tid = threadIdx.x, wid = tid>>6, lane = tid&63;
  hs4[tid] = ((const float4*)hin)[tid];
  int tl = wid & 3, khalf = wid >> 2;
  int t = blockIdx.x*4 + tl;
  // issue all 16 Whh loads first (independent of LDS)
  float4 wv[4][4];
  #pragma unroll
  for (int g=0; g<4; ++g){
    const float4* wr = (const float4*)(Whh + ((size_t)(g*HID + t))*HID) + khalf*256;
    #pragma unroll
    for (int it=0; it<4; ++it) wv[g][it] = wr[it*64 + lane];
  }
  __syncthreads();
  float4 hv[4];
  #pragma unroll
  for (int it=0; it<4; ++it) hv[it] = hs4[khalf*256 + it*64 + lane];
  float acc[4] = {0.f,0.f,0.f,0.f};
  #pragma unroll
  for (int g=0; g<4; ++g){
    #pragma unroll
    for (int it=0; it<4; ++it) acc[g] += dot4(wv[g][it], hv[it]);
  }
  #pragma unroll
  for (int g=0; g<4; ++g){
    float v = wave_reduce(acc[g]);
    if (lane==0) red[wid][g] = v;
  }
  __syncthreads();
  if (tid < 4){
    int t2 = blockIdx.x*4 + tid;
    int xi = xidx[0];
    const float* Pr = P + (size_t)xi*4*HID;
    float gi = red[tid][0]+red[tid+4][0] + Pr[t2];
    float gf = red[tid][1]+red[tid+4][1] + Pr[HID+t2];
    float gg = red[tid][2]+red[tid+4][2] + Pr[2*HID+t2];
    float go = red[tid][3]+red[tid+4][3] + Pr[3*HID+t2];
    float si = 1.f/(1.f+expf(-gi));
    float sf = 1.f/(1.f+expf(-gf));
    float so = 1.f/(1.f+expf(-go));
    float c2 = sf*c[t2] + si*tanhf(gg);
    float h2 = so*tanhf(c2);
    c[t2]=c2; hout[t2]=h2;
  }
}

// ---------------- fused hproj + attn logits + sample ----------------
// phase1: R2-proven shape (512 blocks x 256 thr, wave per j, full-K batched loads)
__global__ __launch_bounds__(256) void attn_fused_kernel(const float* __restrict__ Wh,
                                                         const float* __restrict__ h,
                                                         const float* __restrict__ E,
                                                         const float* __restrict__ Wv,
                                                         float* __restrict__ a,
                                                         int* counter,
                                                         float* sc, uint32_t* key, int* xidx,
                                                         int* action_slot, int k){
  __shared__ float4 hs4[512];
  __shared__ float sfin[8];
  __shared__ int islast;
  int tid = threadIdx.x, wid = tid>>6, lane = tid&63;
  int j = blockIdx.x*4 + wid;
  // issue W loads first
  const float4* W4 = (const float4*)(Wh + (size_t)j*HID);
  float4 wv[8];
  #pragma unroll
  for (int it=0; it<8; ++it) wv[it] = W4[it*64+lane];
  hs4[tid] = ((const float4*)h)[tid];
  hs4[tid+256] = ((const float4*)h)[tid+256];
  __syncthreads();
  float acc = 0.f;
  #pragma unroll
  for (int it=0; it<8; ++it) acc += dot4(wv[it], hs4[it*64+lane]);
  acc = wave_reduce(acc);
  if (lane==0) a[j] = acc;
  __syncthreads();
  if (tid==0){
    __threadfence();
    int prev = atomicAdd(counter, 1);
    islast = (prev == (int)gridDim.x - 1);
  }
  __syncthreads();
  if (!islast) return;
  __threadfence();
  #pragma unroll
  for (int rep=0; rep<2; ++rep){
    int i = wid + rep*4;
    if (i < k){
      float s = 0.f;
      for (int j2 = lane; j2 < HID; j2 += 64)
        s += tanhf(E[(size_t)i*HID + j2] + a[j2]) * Wv[j2];
      s = wave_reduce(s);
      if (lane==0) sfin[i] = s;
    }
  }
  __syncthreads();
  if (tid==0){
    float logits[8];
    for (int i=0;i<k;i++) logits[i] = 2.5f * tanhf(sfin[i] * 0.2f);
    do_sample(logits, k, key, sc, action_slot, xidx, 0);
  }
}

// ---------------- fused op logits + sample (11 blocks, last-block) ----------------
__global__ __launch_bounds__(256) void op_fused_kernel(const float* __restrict__ Wsoft,
                                                       const float* __restrict__ bsoft,
                                                       const float* __restrict__ h,
                                                       float* __restrict__ raw,
                                                       int* counter,
                                                       float* sc, uint32_t* key, int* xidx,
                                                       int* action_slot){
  __shared__ float red[4];
  __shared__ int islast;
  int i = blockIdx.x;
  int tid = threadIdx.x, wid = tid>>6, lane = tid&63;
  const float4* W4 = (const float4*)(Wsoft + (size_t)i*HID) + wid*128;
  const float4* h4 = (const float4*)h + wid*128;
  float4 wv[2], hv[2];
  #pragma unroll
  for (int it=0; it<2; ++it){ wv[it]=W4[it*64+lane]; hv[it]=h4[it*64+lane]; }
  float acc = dot4(wv[0],hv[0]) + dot4(wv[1],hv[1]);
  acc = wave_reduce(acc);
  if (lane==0) red[wid]=acc;
  __syncthreads();
  if (tid==0){
    raw[i] = red[0]+red[1]+red[2]+red[3] + bsoft[i];
    __threadfence();
    int prev = atomicAdd(counter, 1);
    islast = (prev == (int)gridDim.x - 1);
  }
  __syncthreads();
  if (!islast) return;
  if (tid==0){
    __threadfence();
    float logits[11];
    for (int q=0;q<11;q++) logits[q] = tanhf(raw[q] * 0.2f);
    do_sample(logits, 11, key, sc, action_slot, xidx, 8);
  }
}

// ---------------- write outputs ----------------
__global__ void finalize_kernel(const int* __restrict__ actions, const float* __restrict__ sc,
                                float* __restrict__ out){
  int tid = threadIdx.x;
  if (tid < 28) out[tid] = (float)actions[tid];
  if (tid == 28) out[28] = sc[0];
  if (tid == 29) out[29] = sc[1];
}

extern "C" void kernel_launch(void* const* d_in, const int* in_sizes, int n_in,
                              void* d_out, int out_size, void* d_ws, size_t ws_size,
                              hipStream_t stream) {
  const float* emb   = (const float*)d_in[0];
  const float* Wq    = (const float*)d_in[1];
  const float* Wh    = (const float*)d_in[2];
  const float* Wv    = (const float*)d_in[3];
  const float* Wsoft = (const float*)d_in[4];
  const float* bsoft = (const float*)d_in[5];
  const float* Wih   = (const float*)d_in[6];
  const float* Whh   = (const float*)d_in[7];
  const float* bih   = (const float*)d_in[8];
  const float* bhh   = (const float*)d_in[9];
  float* out = (float*)d_out;

  float* ws = (float*)d_ws;
  float* h0      = ws;                    // 2048
  float* h1      = h0 + HID;              // 2048
  float* c       = h1 + HID;              // 2048
  float* E       = c  + HID;              // 8*2048
  float* P       = E  + 8*HID;            // 20*8192
  float* a       = P  + 20*4*HID;         // 2048
  float* raw     = a + HID;               // 16
  float* sc      = raw + 16;              // 2
  uint32_t* key  = (uint32_t*)(sc + 2);   // 2
  int* xidx      = (int*)(sc + 4);        // 1
  int* actions   = (int*)(sc + 5);        // 28
  int* counters  = (int*)(sc + 33);       // 32

  init_kernel<<<8,256,0,stream>>>(h0, c, sc, key, xidx, counters);
  eproj_kernel<<<512,256,0,stream>>>(emb, Wq, E);
  pproj_kernel<<<1024,256,0,stream>>>(Wih, emb, bih, bhh, P);

  float* hbuf[2] = {h0, h1};
  int cur = 0, ns = 0, os = 0, step = 0;
  for (int node = 0; node < 7; ++node){
    for (int i = 0; i < 2; ++i){
      lstm_kernel<<<512,512,0,stream>>>(Whh, P, xidx, hbuf[cur], hbuf[cur^1], c);
      cur ^= 1;
      attn_fused_kernel<<<512,256,0,stream>>>(Wh, hbuf[cur], E, Wv, a,
                                              counters + step, sc, key, xidx,
                                              actions + ns, node + 2);
      step++; ns++;
    }
    for (int i = 0; i < 2; ++i){
      lstm_kernel<<<512,512,0,stream>>>(Whh, P, xidx, hbuf[cur], hbuf[cur^1], c);
      cur ^= 1;
      op_fused_kernel<<<11,256,0,stream>>>(Wsoft, bsoft, hbuf[cur], raw,
                                           counters + step, sc, key, xidx,
                                           actions + 14 + os);
      step++; os++;
    }
  }
  finalize_kernel<<<1,64,0,stream>>>(actions, sc, out);
}

// Round 5
// 748.438 us; speedup vs baseline: 2.0471x; 1.6045x over previous
//
#include <hip/hip_runtime.h>
#include <stdint.h>

#define HID 2048

// ---------------- threefry2x32 (JAX-compatible) ----------------
__device__ __forceinline__ uint32_t rotl32(uint32_t v, int r){ return (v<<r)|(v>>(32-r)); }

__device__ __forceinline__ void tf2x32(uint32_t k0, uint32_t k1, uint32_t x0, uint32_t x1,
                                       uint32_t& o0, uint32_t& o1){
  uint32_t ks2 = k0 ^ k1 ^ 0x1BD11BDAu;
  x0 += k0; x1 += k1;
  x0+=x1; x1=rotl32(x1,13); x1^=x0;
  x0+=x1; x1=rotl32(x1,15); x1^=x0;
  x0+=x1; x1=rotl32(x1,26); x1^=x0;
  x0+=x1; x1=rotl32(x1,6);  x1^=x0;
  x0+=k1; x1+=ks2+1u;
  x0+=x1; x1=rotl32(x1,17); x1^=x0;
  x0+=x1; x1=rotl32(x1,29); x1^=x0;
  x0+=x1; x1=rotl32(x1,16); x1^=x0;
  x0+=x1; x1=rotl32(x1,24); x1^=x0;
  x0+=ks2; x1+=k0+2u;
  x0+=x1; x1=rotl32(x1,13); x1^=x0;
  x0+=x1; x1=rotl32(x1,15); x1^=x0;
  x0+=x1; x1=rotl32(x1,26); x1^=x0;
  x0+=x1; x1=rotl32(x1,6);  x1^=x0;
  x0+=k0; x1+=k1+3u;
  x0+=x1; x1=rotl32(x1,17); x1^=x0;
  x0+=x1; x1=rotl32(x1,29); x1^=x0;
  x0+=x1; x1=rotl32(x1,16); x1^=x0;
  x0+=x1; x1=rotl32(x1,24); x1^=x0;
  x0+=k1; x1+=ks2+4u;
  x0+=x1; x1=rotl32(x1,13); x1^=x0;
  x0+=x1; x1=rotl32(x1,15); x1^=x0;
  x0+=x1; x1=rotl32(x1,26); x1^=x0;
  x0+=x1; x1=rotl32(x1,6);  x1^=x0;
  x0+=ks2; x1+=k0+5u;
  o0=x0; o1=x1;
}

// jax.random.categorical, jax_threefry_partitionable=True (verified: absmax 0 in R2/R3/R4)
__device__ void do_sample(const float* logits, int k, uint32_t* key, float* sc,
                          int* action_out, int* xidx, int xoff){
  float m = logits[0];
  for (int i=1;i<k;i++) m = fmaxf(m, logits[i]);
  float se = 0.f;
  for (int i=0;i<k;i++) se += expf(logits[i]-m);
  float lse = logf(se);

  uint32_t n0,n1,s0,s1;
  tf2x32(key[0],key[1],0u,0u,n0,n1);
  tf2x32(key[0],key[1],0u,1u,s0,s1);
  key[0]=n0; key[1]=n1;

  float best=-3.0e38f; int act=0;
  for (int i=0;i<k;i++){
    uint32_t y0,y1; tf2x32(s0,s1,0u,(uint32_t)i,y0,y1);
    uint32_t bits = y0 ^ y1;
    float f = __uint_as_float((bits>>9)|0x3f800000u) - 1.0f;
    float u = fmaxf(f, 1.17549435e-38f);
    float g = -logf(-logf(u));
    float z = logits[i]+g;
    if (z>best){best=z; act=i;}
  }
  float ent=0.f;
  for (int i=0;i<k;i++){ float lp=logits[i]-m-lse; ent -= lp*expf(lp); }
  sc[0] += logits[act]-m-lse;
  sc[1] += ent;
  *action_out = act;
  *xidx = act + xoff;
}

__device__ __forceinline__ float wave_reduce(float v){
  #pragma unroll
  for (int s=32;s;s>>=1) v += __shfl_xor(v, s);
  return v;
}
__device__ __forceinline__ float dot4(float4 a, float4 b){
  return a.x*b.x + a.y*b.y + a.z*b.z + a.w*b.w;
}

// ---------------- init ----------------
__global__ void init_kernel(float* h0, float* c, float* sc, uint32_t* key, int* xidx){
  int tid = blockIdx.x*blockDim.x + threadIdx.x;
  if (tid < HID){ h0[tid]=0.f; c[tid]=0.f; }
  if (tid==0){ sc[0]=0.f; sc[1]=0.f; key[0]=0u; key[1]=42u; xidx[0]=19; }
}

// ---------------- E = emb[0:8] @ W_emb_attn.T ----------------
__global__ __launch_bounds__(256) void eproj_kernel(const float* __restrict__ emb,
                                                    const float* __restrict__ Wq,
                                                    float* __restrict__ E){
  int w = (blockIdx.x*256 + threadIdx.x) >> 6;
  int lane = threadIdx.x & 63;
  if (w >= HID) return;
  const float4* W4 = (const float4*)(Wq + (size_t)w*HID);
  float acc[8];
  #pragma unroll
  for (int i=0;i<8;i++) acc[i]=0.f;
  #pragma unroll
  for (int it=0; it<8; ++it){
    float4 wv = W4[it*64 + lane];
    #pragma unroll
    for (int i=0;i<8;i++){
      float4 ev = ((const float4*)(emb + (size_t)i*HID))[it*64+lane];
      acc[i] += dot4(wv, ev);
    }
  }
  #pragma unroll
  for (int i=0;i<8;i++){
    float v = wave_reduce(acc[i]);
    if (lane==0) E[(size_t)i*HID + w] = v;
  }
}

// ---------------- pproj: LDS-staged emb, 2 rows/wave (R4-proven) ----------------
__global__ __launch_bounds__(256) void pproj_kernel(const float* __restrict__ Wih,
                                                    const float* __restrict__ emb,
                                                    const float* __restrict__ bih,
                                                    const float* __restrict__ bhh,
                                                    float* __restrict__ P){
  __shared__ float4 smem[19*128];
  int tid = threadIdx.x, wid = tid>>6, lane = tid&63;
  int jbase = blockIdx.x*8 + wid*2;
  float acc0[19], acc1[19];
  #pragma unroll
  for (int e=0;e<19;e++){ acc0[e]=0.f; acc1[e]=0.f; }
  for (int ch=0; ch<4; ++ch){
    __syncthreads();
    for (int t = tid; t < 19*128; t += 256){
      int row = t>>7, col = t&127;
      smem[t] = ((const float4*)(emb + (size_t)row*HID + ch*512))[col];
    }
    __syncthreads();
    #pragma unroll
    for (int it=0; it<2; ++it){
      float4 w0 = ((const float4*)(Wih + (size_t)jbase*HID     + ch*512))[it*64+lane];
      float4 w1 = ((const float4*)(Wih + (size_t)(jbase+1)*HID + ch*512))[it*64+lane];
      #pragma unroll
      for (int e=0;e<19;e++){
        float4 ev = smem[e*128 + it*64 + lane];
        acc0[e] += dot4(w0, ev);
        acc1[e] += dot4(w1, ev);
      }
    }
  }
  #pragma unroll
  for (int e=0;e<19;e++){ acc0[e]=wave_reduce(acc0[e]); acc1[e]=wave_reduce(acc1[e]); }
  if (lane==0){
    float b0 = bih[jbase]   + bhh[jbase];
    float b1 = bih[jbase+1] + bhh[jbase+1];
    #pragma unroll
    for (int e=0;e<19;e++){
      P[(size_t)e*4*HID + jbase]   = acc0[e] + b0;
      P[(size_t)e*4*HID + jbase+1] = acc1[e] + b1;
    }
    P[(size_t)19*4*HID + jbase]   = b0;
    P[(size_t)19*4*HID + jbase+1] = b1;
  }
}

// ---------------- LSTM (R4-proven): 512 blocks x 512 thr ----------------
__global__ __launch_bounds__(512,4) void lstm_kernel(const float* __restrict__ Whh,
                                                     const float* __restrict__ P,
                                                     const int* __restrict__ xidx,
                                                     const float* __restrict__ hin,
                                                     float* __restrict__ hout,
                                                     float* __restrict__ c){
  __shared__ float4 hs4[512];
  __shared__ float red[8][4];
  int tid = threadIdx.x, wid = tid>>6, lane = tid&63;
  hs4[tid] = ((const float4*)hin)[tid];
  int tl = wid & 3, khalf = wid >> 2;
  int t = blockIdx.x*4 + tl;
  float4 wv[4][4];
  #pragma unroll
  for (int g=0; g<4; ++g){
    const float4* wr = (const float4*)(Whh + ((size_t)(g*HID + t))*HID) + khalf*256;
    #pragma unroll
    for (int it=0; it<4; ++it) wv[g][it] = wr[it*64 + lane];
  }
  __syncthreads();
  float4 hv[4];
  #pragma unroll
  for (int it=0; it<4; ++it) hv[it] = hs4[khalf*256 + it*64 + lane];
  float acc[4] = {0.f,0.f,0.f,0.f};
  #pragma unroll
  for (int g=0; g<4; ++g){
    #pragma unroll
    for (int it=0; it<4; ++it) acc[g] += dot4(wv[g][it], hv[it]);
  }
  #pragma unroll
  for (int g=0; g<4; ++g){
    float v = wave_reduce(acc[g]);
    if (lane==0) red[wid][g] = v;
  }
  __syncthreads();
  if (tid < 4){
    int t2 = blockIdx.x*4 + tid;
    int xi = xidx[0];
    const float* Pr = P + (size_t)xi*4*HID;
    float gi = red[tid][0]+red[tid+4][0] + Pr[t2];
    float gf = red[tid][1]+red[tid+4][1] + Pr[HID+t2];
    float gg = red[tid][2]+red[tid+4][2] + Pr[2*HID+t2];
    float go = red[tid][3]+red[tid+4][3] + Pr[3*HID+t2];
    float si = 1.f/(1.f+expf(-gi));
    float sf = 1.f/(1.f+expf(-gf));
    float so = 1.f/(1.f+expf(-go));
    float c2 = sf*c[t2] + si*tanhf(gg);
    float h2 = so*tanhf(c2);
    c[t2]=c2; hout[t2]=h2;
  }
}

// ---------------- hproj: a = W_hid_attn @ h (R4 phase-1 shape) ----------------
__global__ __launch_bounds__(256) void hproj_kernel(const float* __restrict__ Wh,
                                                    const float* __restrict__ h,
                                                    float* __restrict__ a){
  __shared__ float4 hs4[512];
  int tid = threadIdx.x, wid = tid>>6, lane = tid&63;
  int j = blockIdx.x*4 + wid;
  const float4* W4 = (const float4*)(Wh + (size_t)j*HID);
  float4 wv[8];
  #pragma unroll
  for (int it=0; it<8; ++it) wv[it] = W4[it*64+lane];
  hs4[tid] = ((const float4*)h)[tid];
  hs4[tid+256] = ((const float4*)h)[tid+256];
  __syncthreads();
  float acc = 0.f;
  #pragma unroll
  for (int it=0; it<8; ++it) acc += dot4(wv[it], hs4[it*64+lane]);
  acc = wave_reduce(acc);
  if (lane==0) a[j] = acc;
}

// ---------------- attn sample: 1 block, 8 waves, row-per-wave ----------------
__global__ __launch_bounds__(512) void attn_sample_kernel(const float* __restrict__ E,
                                                          const float* __restrict__ a,
                                                          const float* __restrict__ Wv,
                                                          float* sc, uint32_t* key, int* xidx,
                                                          int* action_slot, int k){
  __shared__ float4 as4[512];
  __shared__ float4 wv4[512];
  __shared__ float sfin[8];
  int tid = threadIdx.x, wid = tid>>6, lane = tid&63;
  as4[tid] = ((const float4*)a)[tid];
  wv4[tid] = ((const float4*)Wv)[tid];
  __syncthreads();
  if (wid < k){
    const float4* E4 = (const float4*)(E + (size_t)wid*HID);
    float s = 0.f;
    #pragma unroll
    for (int it=0; it<8; ++it){
      float4 ev = E4[it*64+lane];
      float4 av = as4[it*64+lane];
      float4 w  = wv4[it*64+lane];
      s += tanhf(ev.x+av.x)*w.x + tanhf(ev.y+av.y)*w.y
         + tanhf(ev.z+av.z)*w.z + tanhf(ev.w+av.w)*w.w;
    }
    s = wave_reduce(s);
    if (lane==0) sfin[wid] = s;
  }
  __syncthreads();
  if (tid==0){
    float logits[8];
    for (int i=0;i<k;i++) logits[i] = 2.5f * tanhf(sfin[i] * 0.2f);
    do_sample(logits, k, key, sc, action_slot, xidx, 0);
  }
}

// ---------------- op sample: 1 block, 12 waves, row-per-wave ----------------
__global__ __launch_bounds__(768) void op_sample_kernel(const float* __restrict__ Wsoft,
                                                        const float* __restrict__ bsoft,
                                                        const float* __restrict__ h,
                                                        float* sc, uint32_t* key, int* xidx,
                                                        int* action_slot){
  __shared__ float4 hs4[512];
  __shared__ float sfin[11];
  int tid = threadIdx.x, wid = tid>>6, lane = tid&63;
  float4 wv[8];
  if (wid < 11){
    const float4* W4 = (const float4*)(Wsoft + (size_t)wid*HID);
    #pragma unroll
    for (int it=0; it<8; ++it) wv[it] = W4[it*64+lane];
  }
  if (tid < 512) hs4[tid] = ((const float4*)h)[tid];
  __syncthreads();
  if (wid < 11){
    float s = 0.f;
    #pragma unroll
    for (int it=0; it<8; ++it) s += dot4(wv[it], hs4[it*64+lane]);
    s = wave_reduce(s);
    if (lane==0) sfin[wid] = s + bsoft[wid];
  }
  __syncthreads();
  if (tid==0){
    float logits[11];
    for (int q=0;q<11;q++) logits[q] = tanhf(sfin[q] * 0.2f);
    do_sample(logits, 11, key, sc, action_slot, xidx, 8);
  }
}

// ---------------- write outputs ----------------
__global__ void finalize_kernel(const int* __restrict__ actions, const float* __restrict__ sc,
                                float* __restrict__ out){
  int tid = threadIdx.x;
  if (tid < 28) out[tid] = (float)actions[tid];
  if (tid == 28) out[28] = sc[0];
  if (tid == 29) out[29] = sc[1];
}

extern "C" void kernel_launch(void* const* d_in, const int* in_sizes, int n_in,
                              void* d_out, int out_size, void* d_ws, size_t ws_size,
                              hipStream_t stream) {
  const float* emb   = (const float*)d_in[0];
  const float* Wq    = (const float*)d_in[1];
  const float* Wh    = (const float*)d_in[2];
  const float* Wv    = (const float*)d_in[3];
  const float* Wsoft = (const float*)d_in[4];
  const float* bsoft = (const float*)d_in[5];
  const float* Wih   = (const float*)d_in[6];
  const float* Whh   = (const float*)d_in[7];
  const float* bih   = (const float*)d_in[8];
  const float* bhh   = (const float*)d_in[9];
  float* out = (float*)d_out;

  float* ws = (float*)d_ws;
  float* h0      = ws;                    // 2048
  float* h1      = h0 + HID;              // 2048
  float* c       = h1 + HID;              // 2048
  float* E       = c  + HID;              // 8*2048
  float* P       = E  + 8*HID;            // 20*8192
  float* a       = P  + 20*4*HID;         // 2048
  float* sc      = a + HID;               // 2
  uint32_t* key  = (uint32_t*)(sc + 2);   // 2
  int* xidx      = (int*)(sc + 4);        // 1
  int* actions   = (int*)(sc + 5);        // 28

  init_kernel<<<8,256,0,stream>>>(h0, c, sc, key, xidx);
  eproj_kernel<<<512,256,0,stream>>>(emb, Wq, E);
  pproj_kernel<<<1024,256,0,stream>>>(Wih, emb, bih, bhh, P);

  float* hbuf[2] = {h0, h1};
  int cur = 0, ns = 0, os = 0;
  for (int node = 0; node < 7; ++node){
    for (int i = 0; i < 2; ++i){
      lstm_kernel<<<512,512,0,stream>>>(Whh, P, xidx, hbuf[cur], hbuf[cur^1], c);
      cur ^= 1;
      hproj_kernel<<<512,256,0,stream>>>(Wh, hbuf[cur], a);
      attn_sample_kernel<<<1,512,0,stream>>>(E, a, Wv, sc, key, xidx,
                                             actions + ns, node + 2);
      ns++;
    }
    for (int i = 0; i < 2; ++i){
      lstm_kernel<<<512,512,0,stream>>>(Whh, P, xidx, hbuf[cur], hbuf[cur^1], c);
      cur ^= 1;
      op_sample_kernel<<<1,768,0,stream>>>(Wsoft, bsoft, hbuf[cur], sc, key, xidx,
                                           actions + 14 + os);
      os++;
    }
  }
  finalize_kernel<<<1,64,0,stream>>>(actions, sc, out);
}

// Round 6
// 589.879 us; speedup vs baseline: 2.5973x; 1.2688x over previous
//
#include <hip/hip_runtime.h>
#include <stdint.h>
#include <string.h>

#define HID 2048

typedef __attribute__((ext_vector_type(8))) unsigned short u16x8;

__device__ __forceinline__ float h2f(unsigned short u){
  _Float16 f; __builtin_memcpy(&f, &u, 2); return (float)f;
}
__device__ __forceinline__ unsigned short f2h(float f){
  _Float16 g = (_Float16)f; unsigned short u; __builtin_memcpy(&u, &g, 2); return u;
}

// ---------------- threefry2x32 (JAX-compatible) ----------------
__device__ __forceinline__ uint32_t rotl32(uint32_t v, int r){ return (v<<r)|(v>>(32-r)); }

__device__ __forceinline__ void tf2x32(uint32_t k0, uint32_t k1, uint32_t x0, uint32_t x1,
                                       uint32_t& o0, uint32_t& o1){
  uint32_t ks2 = k0 ^ k1 ^ 0x1BD11BDAu;
  x0 += k0; x1 += k1;
  x0+=x1; x1=rotl32(x1,13); x1^=x0;
  x0+=x1; x1=rotl32(x1,15); x1^=x0;
  x0+=x1; x1=rotl32(x1,26); x1^=x0;
  x0+=x1; x1=rotl32(x1,6);  x1^=x0;
  x0+=k1; x1+=ks2+1u;
  x0+=x1; x1=rotl32(x1,17); x1^=x0;
  x0+=x1; x1=rotl32(x1,29); x1^=x0;
  x0+=x1; x1=rotl32(x1,16); x1^=x0;
  x0+=x1; x1=rotl32(x1,24); x1^=x0;
  x0+=ks2; x1+=k0+2u;
  x0+=x1; x1=rotl32(x1,13); x1^=x0;
  x0+=x1; x1=rotl32(x1,15); x1^=x0;
  x0+=x1; x1=rotl32(x1,26); x1^=x0;
  x0+=x1; x1=rotl32(x1,6);  x1^=x0;
  x0+=k0; x1+=k1+3u;
  x0+=x1; x1=rotl32(x1,17); x1^=x0;
  x0+=x1; x1=rotl32(x1,29); x1^=x0;
  x0+=x1; x1=rotl32(x1,16); x1^=x0;
  x0+=x1; x1=rotl32(x1,24); x1^=x0;
  x0+=k1; x1+=ks2+4u;
  x0+=x1; x1=rotl32(x1,13); x1^=x0;
  x0+=x1; x1=rotl32(x1,15); x1^=x0;
  x0+=x1; x1=rotl32(x1,26); x1^=x0;
  x0+=x1; x1=rotl32(x1,6);  x1^=x0;
  x0+=ks2; x1+=k0+5u;
  o0=x0; o1=x1;
}

// jax.random.categorical, jax_threefry_partitionable=True (verified: absmax 0 in R2-R5)
__device__ void do_sample(const float* logits, int k, uint32_t* key, float* sc,
                          int* action_out, int* xidx, int xoff){
  float m = logits[0];
  for (int i=1;i<k;i++) m = fmaxf(m, logits[i]);
  float se = 0.f;
  for (int i=0;i<k;i++) se += expf(logits[i]-m);
  float lse = logf(se);

  uint32_t n0,n1,s0,s1;
  tf2x32(key[0],key[1],0u,0u,n0,n1);
  tf2x32(key[0],key[1],0u,1u,s0,s1);
  key[0]=n0; key[1]=n1;

  float best=-3.0e38f; int act=0;
  for (int i=0;i<k;i++){
    uint32_t y0,y1; tf2x32(s0,s1,0u,(uint32_t)i,y0,y1);
    uint32_t bits = y0 ^ y1;
    float f = __uint_as_float((bits>>9)|0x3f800000u) - 1.0f;
    float u = fmaxf(f, 1.17549435e-38f);
    float g = -logf(-logf(u));
    float z = logits[i]+g;
    if (z>best){best=z; act=i;}
  }
  float ent=0.f;
  for (int i=0;i<k;i++){ float lp=logits[i]-m-lse; ent -= lp*expf(lp); }
  sc[0] += logits[act]-m-lse;
  sc[1] += ent;
  *action_out = act;
  *xidx = act + xoff;
}

__device__ __forceinline__ float wave_reduce(float v){
  #pragma unroll
  for (int s=32;s;s>>=1) v += __shfl_xor(v, s);
  return v;
}
__device__ __forceinline__ float dot4(float4 a, float4 b){
  return a.x*b.x + a.y*b.y + a.z*b.z + a.w*b.w;
}

// ---------------- weight conversion f32 -> f16 (Whh then Wh) ----------------
__global__ __launch_bounds__(256) void conv_kernel(const float* __restrict__ A,
                                                   const float* __restrict__ B,
                                                   unsigned short* __restrict__ oA,
                                                   unsigned short* __restrict__ oB,
                                                   int nA8, int nTot8){
  int i = blockIdx.x*256 + threadIdx.x;
  if (i >= nTot8) return;
  const float4* src; unsigned short* dst;
  if (i < nA8){ src = (const float4*)A + (size_t)i*2; dst = oA + (size_t)i*8; }
  else { int q = i - nA8; src = (const float4*)B + (size_t)q*2; dst = oB + (size_t)q*8; }
  float4 lo = src[0], hi = src[1];
  u16x8 o;
  o[0]=f2h(lo.x); o[1]=f2h(lo.y); o[2]=f2h(lo.z); o[3]=f2h(lo.w);
  o[4]=f2h(hi.x); o[5]=f2h(hi.y); o[6]=f2h(hi.z); o[7]=f2h(hi.w);
  *(u16x8*)dst = o;
}

// ---------------- init ----------------
__global__ void init_kernel(float* h0, float* c, float* sc, uint32_t* key, int* xidx){
  int tid = blockIdx.x*blockDim.x + threadIdx.x;
  if (tid < HID){ h0[tid]=0.f; c[tid]=0.f; }
  if (tid==0){ sc[0]=0.f; sc[1]=0.f; key[0]=0u; key[1]=42u; xidx[0]=19; }
}

// ---------------- E = emb[0:8] @ W_emb_attn.T ----------------
__global__ __launch_bounds__(256) void eproj_kernel(const float* __restrict__ emb,
                                                    const float* __restrict__ Wq,
                                                    float* __restrict__ E){
  int w = (blockIdx.x*256 + threadIdx.x) >> 6;
  int lane = threadIdx.x & 63;
  if (w >= HID) return;
  const float4* W4 = (const float4*)(Wq + (size_t)w*HID);
  float acc[8];
  #pragma unroll
  for (int i=0;i<8;i++) acc[i]=0.f;
  #pragma unroll
  for (int it=0; it<8; ++it){
    float4 wv = W4[it*64 + lane];
    #pragma unroll
    for (int i=0;i<8;i++){
      float4 ev = ((const float4*)(emb + (size_t)i*HID))[it*64+lane];
      acc[i] += dot4(wv, ev);
    }
  }
  #pragma unroll
  for (int i=0;i<8;i++){
    float v = wave_reduce(acc[i]);
    if (lane==0) E[(size_t)i*HID + w] = v;
  }
}

// ---------------- pproj: LDS-staged emb, 2 rows/wave (R4/R5-proven) ----------------
__global__ __launch_bounds__(256) void pproj_kernel(const float* __restrict__ Wih,
                                                    const float* __restrict__ emb,
                                                    const float* __restrict__ bih,
                                                    const float* __restrict__ bhh,
                                                    float* __restrict__ P){
  __shared__ float4 smem[19*128];
  int tid = threadIdx.x, wid = tid>>6, lane = tid&63;
  int jbase = blockIdx.x*8 + wid*2;
  float acc0[19], acc1[19];
  #pragma unroll
  for (int e=0;e<19;e++){ acc0[e]=0.f; acc1[e]=0.f; }
  for (int ch=0; ch<4; ++ch){
    __syncthreads();
    for (int t = tid; t < 19*128; t += 256){
      int row = t>>7, col = t&127;
      smem[t] = ((const float4*)(emb + (size_t)row*HID + ch*512))[col];
    }
    __syncthreads();
    #pragma unroll
    for (int it=0; it<2; ++it){
      float4 w0 = ((const float4*)(Wih + (size_t)jbase*HID     + ch*512))[it*64+lane];
      float4 w1 = ((const float4*)(Wih + (size_t)(jbase+1)*HID + ch*512))[it*64+lane];
      #pragma unroll
      for (int e=0;e<19;e++){
        float4 ev = smem[e*128 + it*64 + lane];
        acc0[e] += dot4(w0, ev);
        acc1[e] += dot4(w1, ev);
      }
    }
  }
  #pragma unroll
  for (int e=0;e<19;e++){ acc0[e]=wave_reduce(acc0[e]); acc1[e]=wave_reduce(acc1[e]); }
  if (lane==0){
    float b0 = bih[jbase]   + bhh[jbase];
    float b1 = bih[jbase+1] + bhh[jbase+1];
    #pragma unroll
    for (int e=0;e<19;e++){
      P[(size_t)e*4*HID + jbase]   = acc0[e] + b0;
      P[(size_t)e*4*HID + jbase+1] = acc1[e] + b1;
    }
    P[(size_t)19*4*HID + jbase]   = b0;
    P[(size_t)19*4*HID + jbase+1] = b1;
  }
}

// ---------------- LSTM fp16 weights: 512 blocks x 512 thr (R4 shape) ----------------
__global__ __launch_bounds__(512,4) void lstm_h16_kernel(const unsigned short* __restrict__ Whh16,
                                                         const float* __restrict__ P,
                                                         const int* __restrict__ xidx,
                                                         const float* __restrict__ hin,
                                                         float* __restrict__ hout,
                                                         float* __restrict__ c){
  __shared__ float4 hs4[512];
  __shared__ float red[8][4];
  int tid = threadIdx.x, wid = tid>>6, lane = tid&63;
  hs4[tid] = ((const float4*)hin)[tid];
  int tl = wid & 3, khalf = wid >> 2;
  int t = blockIdx.x*4 + tl;
  u16x8 wv[4][2];
  #pragma unroll
  for (int g=0; g<4; ++g){
    const u16x8* wr = (const u16x8*)(Whh16 + ((size_t)(g*HID + t))*HID) + khalf*128;
    wv[g][0] = wr[lane];
    wv[g][1] = wr[64 + lane];
  }
  __syncthreads();
  float4 hv[2][2];
  #pragma unroll
  for (int it=0; it<2; ++it){
    int idx = khalf*256 + (it*64+lane)*2;
    hv[it][0] = hs4[idx]; hv[it][1] = hs4[idx+1];
  }
  float acc[4] = {0.f,0.f,0.f,0.f};
  #pragma unroll
  for (int g=0; g<4; ++g){
    #pragma unroll
    for (int it=0; it<2; ++it){
      u16x8 w = wv[g][it];
      acc[g] += h2f(w[0])*hv[it][0].x + h2f(w[1])*hv[it][0].y
              + h2f(w[2])*hv[it][0].z + h2f(w[3])*hv[it][0].w
              + h2f(w[4])*hv[it][1].x + h2f(w[5])*hv[it][1].y
              + h2f(w[6])*hv[it][1].z + h2f(w[7])*hv[it][1].w;
    }
  }
  #pragma unroll
  for (int g=0; g<4; ++g){
    float v = wave_reduce(acc[g]);
    if (lane==0) red[wid][g] = v;
  }
  __syncthreads();
  if (tid < 4){
    int t2 = blockIdx.x*4 + tid;
    int xi = xidx[0];
    const float* Pr = P + (size_t)xi*4*HID;
    float gi = red[tid][0]+red[tid+4][0] + Pr[t2];
    float gf = red[tid][1]+red[tid+4][1] + Pr[HID+t2];
    float gg = red[tid][2]+red[tid+4][2] + Pr[2*HID+t2];
    float go = red[tid][3]+red[tid+4][3] + Pr[3*HID+t2];
    float si = 1.f/(1.f+expf(-gi));
    float sf = 1.f/(1.f+expf(-gf));
    float so = 1.f/(1.f+expf(-go));
    float c2 = sf*c[t2] + si*tanhf(gg);
    float h2 = so*tanhf(c2);
    c[t2]=c2; hout[t2]=h2;
  }
}

// ---------------- LSTM f32 fallback (R5-proven) ----------------
__global__ __launch_bounds__(512,4) void lstm_kernel(const float* __restrict__ Whh,
                                                     const float* __restrict__ P,
                                                     const int* __restrict__ xidx,
                                                     const float* __restrict__ hin,
                                                     float* __restrict__ hout,
                                                     float* __restrict__ c){
  __shared__ float4 hs4[512];
  __shared__ float red[8][4];
  int tid = threadIdx.x, wid = tid>>6, lane = tid&63;
  hs4[tid] = ((const float4*)hin)[tid];
  int tl = wid & 3, khalf = wid >> 2;
  int t = blockIdx.x*4 + tl;
  float4 wv[4][4];
  #pragma unroll
  for (int g=0; g<4; ++g){
    const float4* wr = (const float4*)(Whh + ((size_t)(g*HID + t))*HID) + khalf*256;
    #pragma unroll
    for (int it=0; it<4; ++it) wv[g][it] = wr[it*64 + lane];
  }
  __syncthreads();
  float4 hv[4];
  #pragma unroll
  for (int it=0; it<4; ++it) hv[it] = hs4[khalf*256 + it*64 + lane];
  float acc[4] = {0.f,0.f,0.f,0.f};
  #pragma unroll
  for (int g=0; g<4; ++g){
    #pragma unroll
    for (int it=0; it<4; ++it) acc[g] += dot4(wv[g][it], hv[it]);
  }
  #pragma unroll
  for (int g=0; g<4; ++g){
    float v = wave_reduce(acc[g]);
    if (lane==0) red[wid][g] = v;
  }
  __syncthreads();
  if (tid < 4){
    int t2 = blockIdx.x*4 + tid;
    int xi = xidx[0];
    const float* Pr = P + (size_t)xi*4*HID;
    float gi = red[tid][0]+red[tid+4][0] + Pr[t2];
    float gf = red[tid][1]+red[tid+4][1] + Pr[HID+t2];
    float gg = red[tid][2]+red[tid+4][2] + Pr[2*HID+t2];
    float go = red[tid][3]+red[tid+4][3] + Pr[3*HID+t2];
    float si = 1.f/(1.f+expf(-gi));
    float sf = 1.f/(1.f+expf(-gf));
    float so = 1.f/(1.f+expf(-go));
    float c2 = sf*c[t2] + si*tanhf(gg);
    float h2 = so*tanhf(c2);
    c[t2]=c2; hout[t2]=h2;
  }
}

// ---------------- hproj fp16 weights ----------------
__global__ __launch_bounds__(256) void hproj_h16_kernel(const unsigned short* __restrict__ Wh16,
                                                        const float* __restrict__ h,
                                                        float* __restrict__ a){
  __shared__ float4 hs4[512];
  int tid = threadIdx.x, wid = tid>>6, lane = tid&63;
  int j = blockIdx.x*4 + wid;
  const u16x8* W8 = (const u16x8*)(Wh16 + (size_t)j*HID);
  u16x8 wv[4];
  #pragma unroll
  for (int it=0; it<4; ++it) wv[it] = W8[it*64+lane];
  hs4[tid] = ((const float4*)h)[tid];
  hs4[tid+256] = ((const float4*)h)[tid+256];
  __syncthreads();
  float acc = 0.f;
  #pragma unroll
  for (int it=0; it<4; ++it){
    int idx = (it*64+lane)*2;
    float4 h0 = hs4[idx], h1 = hs4[idx+1];
    u16x8 w = wv[it];
    acc += h2f(w[0])*h0.x + h2f(w[1])*h0.y + h2f(w[2])*h0.z + h2f(w[3])*h0.w
         + h2f(w[4])*h1.x + h2f(w[5])*h1.y + h2f(w[6])*h1.z + h2f(w[7])*h1.w;
  }
  acc = wave_reduce(acc);
  if (lane==0) a[j] = acc;
}

// ---------------- hproj f32 fallback (R5-proven) ----------------
__global__ __launch_bounds__(256) void hproj_kernel(const float* __restrict__ Wh,
                                                    const float* __restrict__ h,
                                                    float* __restrict__ a){
  __shared__ float4 hs4[512];
  int tid = threadIdx.x, wid = tid>>6, lane = tid&63;
  int j = blockIdx.x*4 + wid;
  const float4* W4 = (const float4*)(Wh + (size_t)j*HID);
  float4 wv[8];
  #pragma unroll
  for (int it=0; it<8; ++it) wv[it] = W4[it*64+lane];
  hs4[tid] = ((const float4*)h)[tid];
  hs4[tid+256] = ((const float4*)h)[tid+256];
  __syncthreads();
  float acc = 0.f;
  #pragma unroll
  for (int it=0; it<8; ++it) acc += dot4(wv[it], hs4[it*64+lane]);
  acc = wave_reduce(acc);
  if (lane==0) a[j] = acc;
}

// ---------------- attn sample: 1 block, 8 waves ----------------
__global__ __launch_bounds__(512) void attn_sample_kernel(const float* __restrict__ E,
                                                          const float* __restrict__ a,
                                                          const float* __restrict__ Wv,
                                                          float* sc, uint32_t* key, int* xidx,
                                                          int* action_slot, int k){
  __shared__ float4 as4[512];
  __shared__ float4 wv4[512];
  __shared__ float sfin[8];
  int tid = threadIdx.x, wid = tid>>6, lane = tid&63;
  as4[tid] = ((const float4*)a)[tid];
  wv4[tid] = ((const float4*)Wv)[tid];
  __syncthreads();
  if (wid < k){
    const float4* E4 = (const float4*)(E + (size_t)wid*HID);
    float s = 0.f;
    #pragma unroll
    for (int it=0; it<8; ++it){
      float4 ev = E4[it*64+lane];
      float4 av = as4[it*64+lane];
      float4 w  = wv4[it*64+lane];
      s += tanhf(ev.x+av.x)*w.x + tanhf(ev.y+av.y)*w.y
         + tanhf(ev.z+av.z)*w.z + tanhf(ev.w+av.w)*w.w;
    }
    s = wave_reduce(s);
    if (lane==0) sfin[wid] = s;
  }
  __syncthreads();
  if (tid==0){
    float logits[8];
    for (int i=0;i<k;i++) logits[i] = 2.5f * tanhf(sfin[i] * 0.2f);
    do_sample(logits, k, key, sc, action_slot, xidx, 0);
  }
}

// ---------------- op sample: 1 block, 12 waves ----------------
__global__ __launch_bounds__(768) void op_sample_kernel(const float* __restrict__ Wsoft,
                                                        const float* __restrict__ bsoft,
                                                        const float* __restrict__ h,
                                                        float* sc, uint32_t* key, int* xidx,
                                                        int* action_slot){
  __shared__ float4 hs4[512];
  __shared__ float sfin[11];
  int tid = threadIdx.x, wid = tid>>6, lane = tid&63;
  float4 wv[8];
  if (wid < 11){
    const float4* W4 = (const float4*)(Wsoft + (size_t)wid*HID);
    #pragma unroll
    for (int it=0; it<8; ++it) wv[it] = W4[it*64+lane];
  }
  if (tid < 512) hs4[tid] = ((const float4*)h)[tid];
  __syncthreads();
  if (wid < 11){
    float s = 0.f;
    #pragma unroll
    for (int it=0; it<8; ++it) s += dot4(wv[it], hs4[it*64+lane]);
    s = wave_reduce(s);
    if (lane==0) sfin[wid] = s + bsoft[wid];
  }
  __syncthreads();
  if (tid==0){
    float logits[11];
    for (int q=0;q<11;q++) logits[q] = tanhf(sfin[q] * 0.2f);
    do_sample(logits, 11, key, sc, action_slot, xidx, 8);
  }
}

// ---------------- write outputs ----------------
__global__ void finalize_kernel(const int* __restrict__ actions, const float* __restrict__ sc,
                                float* __restrict__ out){
  int tid = threadIdx.x;
  if (tid < 28) out[tid] = (float)actions[tid];
  if (tid == 28) out[28] = sc[0];
  if (tid == 29) out[29] = sc[1];
}

extern "C" void kernel_launch(void* const* d_in, const int* in_sizes, int n_in,
                              void* d_out, int out_size, void* d_ws, size_t ws_size,
                              hipStream_t stream) {
  const float* emb   = (const float*)d_in[0];
  const float* Wq    = (const float*)d_in[1];
  const float* Wh    = (const float*)d_in[2];
  const float* Wv    = (const float*)d_in[3];
  const float* Wsoft = (const float*)d_in[4];
  const float* bsoft = (const float*)d_in[5];
  const float* Wih   = (const float*)d_in[6];
  const float* Whh   = (const float*)d_in[7];
  const float* bih   = (const float*)d_in[8];
  const float* bhh   = (const float*)d_in[9];
  float* out = (float*)d_out;

  const size_t nWhh = (size_t)4*HID*HID;       // 16,777,216
  const size_t nWh  = (size_t)HID*HID;         //  4,194,304
  const size_t floatAreaBytes = (size_t)(3*HID + 8*HID + 20*4*HID + HID + 64) * 4;
  const size_t halfBytes = (nWhh + nWh) * 2;   // ~42 MB
  bool use16 = (ws_size >= halfBytes + floatAreaBytes);

  unsigned short* Whh16 = (unsigned short*)d_ws;
  unsigned short* Wh16  = Whh16 + nWhh;
  float* fbase = (float*)((char*)d_ws + (use16 ? halfBytes : 0));

  float* h0      = fbase;                 // 2048
  float* h1      = h0 + HID;              // 2048
  float* c       = h1 + HID;              // 2048
  float* E       = c  + HID;              // 8*2048
  float* P       = E  + 8*HID;            // 20*8192
  float* a       = P  + 20*4*HID;         // 2048
  float* sc      = a + HID;               // 2
  uint32_t* key  = (uint32_t*)(sc + 2);   // 2
  int* xidx      = (int*)(sc + 4);        // 1
  int* actions   = (int*)(sc + 5);        // 28

  if (use16){
    int nA8 = (int)(nWhh/8), nTot8 = (int)((nWhh+nWh)/8);
    conv_kernel<<<(nTot8+255)/256,256,0,stream>>>(Whh, Wh, Whh16, Wh16, nA8, nTot8);
  }
  init_kernel<<<8,256,0,stream>>>(h0, c, sc, key, xidx);
  eproj_kernel<<<512,256,0,stream>>>(emb, Wq, E);
  pproj_kernel<<<1024,256,0,stream>>>(Wih, emb, bih, bhh, P);

  float* hbuf[2] = {h0, h1};
  int cur = 0, ns = 0, os = 0;
  for (int node = 0; node < 7; ++node){
    for (int i = 0; i < 2; ++i){
      if (use16) lstm_h16_kernel<<<512,512,0,stream>>>(Whh16, P, xidx, hbuf[cur], hbuf[cur^1], c);
      else       lstm_kernel<<<512,512,0,stream>>>(Whh, P, xidx, hbuf[cur], hbuf[cur^1], c);
      cur ^= 1;
      if (use16) hproj_h16_kernel<<<512,256,0,stream>>>(Wh16, hbuf[cur], a);
      else       hproj_kernel<<<512,256,0,stream>>>(Wh, hbuf[cur], a);
      attn_sample_kernel<<<1,512,0,stream>>>(E, a, Wv, sc, key, xidx,
                                             actions + ns, node + 2);
      ns++;
    }
    for (int i = 0; i < 2; ++i){
      if (use16) lstm_h16_kernel<<<512,512,0,stream>>>(Whh16, P, xidx, hbuf[cur], hbuf[cur^1], c);
      else       lstm_kernel<<<512,512,0,stream>>>(Whh, P, xidx, hbuf[cur], hbuf[cur^1], c);
      cur ^= 1;
      op_sample_kernel<<<1,768,0,stream>>>(Wsoft, bsoft, hbuf[cur], sc, key, xidx,
                                           actions + 14 + os);
      os++;
    }
  }
  finalize_kernel<<<1,64,0,stream>>>(actions, sc, out);
}